// Round 2
// baseline (610.575 us; speedup 1.0000x reference)
//
#include <hip/hip_runtime.h>
#include <hip/hip_bf16.h>

#define N_EL 19
#define C 128
#define E_PER 342

__global__ __launch_bounds__(256) void graphconv_fused(
    const float* __restrict__ x,
    const int*   __restrict__ ei,      // [2, E_total]
    const float* __restrict__ ew,      // [342]
    const float* __restrict__ Wrel,    // [128,128] row-major (C_OUT, C_IN)
    const float* __restrict__ brel,    // [128]
    const float* __restrict__ Wroot,   // [128,128]
    float* __restrict__ out,
    int E_total)
{
    __shared__ float xs[N_EL][C];        // 9728 B  X_g
    __shared__ float ag[N_EL][C];        // 9728 B  agg
    __shared__ float A[N_EL][N_EL + 1];  // adjacency (dst, src), padded

    const int g = blockIdx.x;
    const int t = threadIdx.x;

    // ---- stage X_g into LDS (vectorized, coalesced) ----
    const float4* xg4 = (const float4*)(x + (size_t)g * N_EL * C);
    float4* xs4 = (float4*)&xs[0][0];
    #pragma unroll
    for (int i = t; i < N_EL * C / 4; i += 256) xs4[i] = xg4[i];

    // ---- zero A ----
    for (int i = t; i < N_EL * (N_EL + 1); i += 256) ((float*)A)[i] = 0.f;
    __syncthreads();

    // ---- build A from this graph's 342 edges (342 > 256: strided loop!) ----
    for (int e = t; e < E_PER; e += 256) {
        int ge = g * E_PER + e;
        int s  = ei[ge];             // row 0: src (global node id)
        int d  = ei[E_total + ge];   // row 1: dst
        int sl = s - g * N_EL;
        int dl = d - g * N_EL;
        // rep[ge] = ew[ge % 342] == ew[e] for graph-contiguous edge layout
        A[dl][sl] = ew[e];
    }
    __syncthreads();

    // ---- agg[j][c] = sum_i A[j][i] * xs[i][c]  (19 MACs per output) ----
    #pragma unroll
    for (int idx = t; idx < N_EL * C; idx += 256) {
        int j = idx >> 7, c = idx & 127;
        float s = 0.f;
        #pragma unroll
        for (int i = 0; i < N_EL; ++i) s += A[j][i] * xs[i][c];
        ag[j][c] = s;
    }
    __syncthreads();

    // ---- out[j][co] = b[co] + agg[j]·Wrel[co] + xs[j]·Wroot[co] ----
    float* og = out + (size_t)g * N_EL * C;
    for (int idx = t; idx < N_EL * C; idx += 256) {
        int j = idx >> 7, co = idx & 127;
        const float4* wr4 = (const float4*)(Wrel  + (size_t)co * C);
        const float4* wo4 = (const float4*)(Wroot + (size_t)co * C);
        const float4* a4  = (const float4*)&ag[j][0];
        const float4* x4  = (const float4*)&xs[j][0];
        float s = brel[co];
        #pragma unroll 8
        for (int c4 = 0; c4 < C / 4; ++c4) {
            float4 w1 = wr4[c4], av = a4[c4];
            float4 w2 = wo4[c4], xv = x4[c4];
            s += w1.x * av.x + w1.y * av.y + w1.z * av.z + w1.w * av.w;
            s += w2.x * xv.x + w2.y * xv.y + w2.z * xv.z + w2.w * xv.w;
        }
        og[idx] = s;
    }
}

extern "C" void kernel_launch(void* const* d_in, const int* in_sizes, int n_in,
                              void* d_out, int out_size, void* d_ws, size_t ws_size,
                              hipStream_t stream) {
    const float* x     = (const float*)d_in[0];
    const int*   ei    = (const int*)d_in[1];
    const float* ew    = (const float*)d_in[2];
    const float* Wrel  = (const float*)d_in[3];
    const float* brel  = (const float*)d_in[4];
    const float* Wroot = (const float*)d_in[5];
    float* out = (float*)d_out;

    const int E_total  = in_sizes[1] / 2;          // 615600
    const int n_graphs = E_total / E_PER;          // 1800

    graphconv_fused<<<n_graphs, 256, 0, stream>>>(
        x, ei, ew, Wrel, brel, Wroot, out, E_total);
}

// Round 3
// 115.291 us; speedup vs baseline: 5.2960x; 5.2960x over previous
//
#include <hip/hip_runtime.h>
#include <hip/hip_bf16.h>

#define GPB 4            // graphs per block
#define ROWS 76          // GPB * 19
#define MP 80            // padded to 5 tiles of 16
#define LDK 264          // Amat row stride (bf16 elems), 528 B (16B-aligned, bank-skewed)
#define EPG 342          // edges per graph

typedef short short8 __attribute__((ext_vector_type(8)));
typedef float f32x4  __attribute__((ext_vector_type(4)));

__device__ __forceinline__ unsigned int f2bf(float f) {
    unsigned int u = __float_as_uint(f);
    return (u + 0x7fffu + ((u >> 16) & 1u)) >> 16;   // RNE
}
__device__ __forceinline__ float bf2f(unsigned int h) {
    return __uint_as_float(h << 16);
}
__device__ __forceinline__ int pk2(float lo, float hi) {
    return (int)(f2bf(lo) | (f2bf(hi) << 16));
}

__global__ __launch_bounds__(256) void graphconv_mfma(
    const float* __restrict__ x,
    const int*   __restrict__ ei,      // [2, E_total]
    const float* __restrict__ ew,      // [342]
    const float* __restrict__ Wrel,    // [128,128] row-major (co, ci)
    const float* __restrict__ brel,    // [128]
    const float* __restrict__ Wroot,   // [128,128]
    float* __restrict__ out,
    int E_total)
{
    // Amat[r][k] bf16: k in [0,128) = agg, [128,256) = x. Rows 76..79 = garbage
    // (only feeds C rows 76..79, which are never stored).
    __shared__ __align__(16) unsigned short Amat[MP * LDK];   // 42240 B
    __shared__ float adj[GPB][19][20];                        //  6080 B

    const int t    = threadIdx.x;
    const int lane = t & 63;
    const int wv   = t >> 6;            // wave 0..3
    const int g0   = blockIdx.x * GPB;  // first graph of this block

    // ---- B fragments in registers, straight from global (L2-hot W).
    // mfma A-operand layout: lane holds A[m=lane&15][k=(lane>>4)*8 + j];
    // B-operand mirrors with n=lane&15: lane holds B[k=(lane>>4)*8+j][n] =
    // W[n][k] (row-major W row n, 8 consecutive k) -> two float4 loads + cvt.
    const int lrow = lane & 15;
    const int kq   = (lane >> 4) * 8;
    const int colA = wv * 16 + lrow;         // wave owns col-tiles wv and wv+4
    const int colB = (wv + 4) * 16 + lrow;

    short8 bf[2][2][4];   // [pass rel/root][col-tile][k-step]
    #pragma unroll
    for (int pass = 0; pass < 2; ++pass) {
        const float* W = pass ? Wroot : Wrel;
        #pragma unroll
        for (int ct = 0; ct < 2; ++ct) {
            const float* wr = W + (size_t)(ct ? colB : colA) * 128 + kq;
            #pragma unroll
            for (int ks = 0; ks < 4; ++ks) {
                const float4* p = (const float4*)(wr + ks * 32);
                float4 a = p[0], b = p[1];
                union { short8 s; int i[4]; } u;
                u.i[0] = pk2(a.x, a.y); u.i[1] = pk2(a.z, a.w);
                u.i[2] = pk2(b.x, b.y); u.i[3] = pk2(b.z, b.w);
                bf[pass][ct][ks] = u.s;
            }
        }
    }
    const float bias0 = brel[colA];
    const float bias1 = brel[colB];

    // ---- P1: stage x -> bf16 into Amat[:,128:256); P2a: zero adj ----
    const float4* xg = (const float4*)(x + (size_t)g0 * 19 * 128);
    for (int idx = t; idx < ROWS * 32; idx += 256) {
        int row = idx >> 5, c4 = idx & 31;
        float4 v = xg[idx];
        int2 w; w.x = pk2(v.x, v.y); w.y = pk2(v.z, v.w);
        *(int2*)&Amat[row * LDK + 128 + c4 * 4] = w;
    }
    for (int i = t; i < GPB * 19 * 20; i += 256) ((float*)adj)[i] = 0.f;
    __syncthreads();

    // ---- P2b: scatter this block's 4*342 edges into dense adjacency ----
    for (int e = t; e < GPB * EPG; e += 256) {
        int g  = e / EPG;
        int te = e - g * EPG;              // edge index within graph
        int ge = g0 * EPG + e;             // == (g0+g)*EPG + te
        int nb = (g0 + g) * 19;
        int sl = ei[ge] - nb;              // row 0: src
        int dl = ei[E_total + ge] - nb;    // row 1: dst
        adj[g][dl][sl] = ew[te];           // rep[ge] = ew[ge % 342] = ew[te]
    }
    __syncthreads();

    // ---- P3: agg[j][c] = sum_i adj[j][i] * x[i][c] -> Amat[:,0:128) ----
    // All 64 lanes of a wave share j (128 threads per row) -> adj broadcast,
    // x reads span 32 consecutive words -> 2-way (free).
    for (int idx = t; idx < ROWS * 128; idx += 256) {
        int j = idx >> 7, c = idx & 127;
        int g = j / 19, jl = j - g * 19;
        int bg = g * 19;
        float s = 0.f;
        #pragma unroll
        for (int i = 0; i < 19; ++i)
            s += adj[g][jl][i] * bf2f(Amat[(bg + i) * LDK + 128 + c]);
        Amat[j * LDK + c] = (unsigned short)f2bf(s);
    }
    __syncthreads();

    // ---- P4: C[76x128] = Amat[76x256] * B[256x128] via MFMA 16x16x32 ----
    float* ob = out + (size_t)blockIdx.x * ROWS * 128;
    #pragma unroll
    for (int rt = 0; rt < 5; ++rt) {
        f32x4 acc0 = {0.f, 0.f, 0.f, 0.f};
        f32x4 acc1 = {0.f, 0.f, 0.f, 0.f};
        const unsigned short* ar = Amat + (rt * 16 + lrow) * LDK + kq;
        #pragma unroll
        for (int ks = 0; ks < 8; ++ks) {   // k = ks*32: 0..127 rel, 128..255 root
            short8 a = *(const short8*)(ar + ks * 32);
            int p = ks >> 2, k4 = ks & 3;
            acc0 = __builtin_amdgcn_mfma_f32_16x16x32_bf16(a, bf[p][0][k4], acc0, 0, 0, 0);
            acc1 = __builtin_amdgcn_mfma_f32_16x16x32_bf16(a, bf[p][1][k4], acc1, 0, 0, 0);
        }
        // C/D layout: col = lane&15, row = (lane>>4)*4 + reg  [m89/m91 verified]
        int rbase = rt * 16 + (lane >> 4) * 4;
        #pragma unroll
        for (int r = 0; r < 4; ++r) {
            int row = rbase + r;
            if (row < ROWS) {
                ob[row * 128 + colA] = acc0[r] + bias0;
                ob[row * 128 + colB] = acc1[r] + bias1;
            }
        }
    }
}

extern "C" void kernel_launch(void* const* d_in, const int* in_sizes, int n_in,
                              void* d_out, int out_size, void* d_ws, size_t ws_size,
                              hipStream_t stream) {
    const float* x     = (const float*)d_in[0];
    const int*   ei    = (const int*)d_in[1];
    const float* ew    = (const float*)d_in[2];
    const float* Wrel  = (const float*)d_in[3];
    const float* brel  = (const float*)d_in[4];
    const float* Wroot = (const float*)d_in[5];
    float* out = (float*)d_out;

    const int E_total  = in_sizes[1] / 2;     // 615600
    const int n_graphs = E_total / EPG;       // 1800
    const int n_blocks = n_graphs / GPB;      // 450

    graphconv_mfma<<<n_blocks, 256, 0, stream>>>(
        x, ei, ew, Wrel, brel, Wroot, out, E_total);
}

// Round 4
// 106.799 us; speedup vs baseline: 5.7170x; 1.0795x over previous
//
#include <hip/hip_runtime.h>
#include <hip/hip_bf16.h>

#define GPB 2            // graphs per block
#define ROWS 38          // GPB * 19
#define MP 48            // padded to 3 tiles of 16
#define LDK 264          // Amat row stride (bf16 elems); 528 B/row, rows rotate 4 banks
#define EPG 342          // edges per graph

typedef short short8 __attribute__((ext_vector_type(8)));
typedef float f32x4  __attribute__((ext_vector_type(4)));

static __device__ __forceinline__ unsigned int f2bf(float f) {
    unsigned int u = __float_as_uint(f);
    return (u + 0x7fffu + ((u >> 16) & 1u)) >> 16;   // RNE
}
static __device__ __forceinline__ int pk2(float lo, float hi) {
    return (int)(f2bf(lo) | (f2bf(hi) << 16));
}

__global__ __launch_bounds__(256) void graphconv_mfma(
    const float* __restrict__ x,
    const int*   __restrict__ ei,      // [2, E_total]
    const float* __restrict__ ew,      // [342]
    const float* __restrict__ Wrel,    // [128,128] row-major (co, ci)
    const float* __restrict__ brel,    // [128]
    const float* __restrict__ Wroot,   // [128,128]
    float* __restrict__ out,
    int E_total)
{
    // Amat[r][k] bf16: k in [0,128) = agg, [128,256) = x. Rows 38..47 garbage
    // (feed only C rows 38..47, never stored).
    __shared__ __align__(16) unsigned short Amat[MP * LDK];   // 25344 B
    __shared__ float adj[GPB][19][20];                        //  3040 B

    const int t    = threadIdx.x;
    const int lane = t & 63;
    const int wv   = t >> 6;            // wave 0..3
    const int g0   = blockIdx.x * GPB;

    const int lrow = lane & 15;
    const int kq   = (lane >> 4) * 8;
    const int colA = wv * 16 + lrow;         // wave owns col-tiles wv and wv+4
    const int colB = (wv + 4) * 16 + lrow;

    // ---- B fragments in registers from global (L2-hot W).
    // B-frag layout (m89/m91-verified via R3 pass): lane holds B[k=kq+j][n=lane&15]
    // = W[n][kq+j] -> row-major W row n, 8 consecutive k.
    short8 bf[2][2][4];   // [rel/root][col-tile][k-step]
    #pragma unroll
    for (int pass = 0; pass < 2; ++pass) {
        const float* W = pass ? Wroot : Wrel;
        #pragma unroll
        for (int ct = 0; ct < 2; ++ct) {
            const float* wr = W + (size_t)(ct ? colB : colA) * 128 + kq;
            #pragma unroll
            for (int ks = 0; ks < 4; ++ks) {
                const float4* p = (const float4*)(wr + ks * 32);
                float4 a = p[0], b = p[1];
                union { short8 s; int i[4]; } u;
                u.i[0] = pk2(a.x, a.y); u.i[1] = pk2(a.z, a.w);
                u.i[2] = pk2(b.x, b.y); u.i[3] = pk2(b.z, b.w);
                bf[pass][ct][ks] = u.s;
            }
        }
    }
    const float bias0 = brel[colA];
    const float bias1 = brel[colB];

    // ---- P1: x -> bf16 into Amat[:,128:256); zero adj ----
    const float4* xg = (const float4*)(x + (size_t)g0 * 19 * 128);
    for (int idx = t; idx < ROWS * 32; idx += 256) {
        int row = idx >> 5, c4 = idx & 31;
        float4 v = xg[idx];
        int2 w; w.x = pk2(v.x, v.y); w.y = pk2(v.z, v.w);
        *(int2*)&Amat[row * LDK + 128 + c4 * 4] = w;
    }
    for (int i = t; i < GPB * 19 * 20; i += 256) ((float*)adj)[i] = 0.f;
    __syncthreads();

    // ---- P2: scatter this block's edges into dense adjacency ----
    for (int e = t; e < GPB * EPG; e += 256) {
        int g  = (e >= EPG) ? 1 : 0;
        int te = e - g * EPG;
        int ge = g0 * EPG + e;
        int nb = (g0 + g) * 19;
        int sl = ei[ge] - nb;              // row 0: src
        int dl = ei[E_total + ge] - nb;    // row 1: dst
        adj[g][dl][sl] = ew[te];           // rep[ge] = ew[ge % 342] = ew[te]
    }
    __syncthreads();

    // ---- P3: agg[j][c] = sum_i adj[j][i]*x[i][c], b128-vectorized, 8 accs ----
    for (int idx = t; idx < ROWS * 16; idx += 256) {
        int j = idx >> 4, c8 = idx & 15;
        int g = (j >= 19) ? 1 : 0;
        int jl = j - g * 19;
        int bg = g * 19;
        float acc[8];
        #pragma unroll
        for (int q = 0; q < 8; ++q) acc[q] = 0.f;
        #pragma unroll 4
        for (int i = 0; i < 19; ++i) {
            float a = adj[g][jl][i];
            int4 w = *(const int4*)&Amat[(bg + i) * LDK + 128 + c8 * 8];
            acc[0] += a * __uint_as_float((unsigned)w.x << 16);
            acc[1] += a * __uint_as_float((unsigned)w.x & 0xffff0000u);
            acc[2] += a * __uint_as_float((unsigned)w.y << 16);
            acc[3] += a * __uint_as_float((unsigned)w.y & 0xffff0000u);
            acc[4] += a * __uint_as_float((unsigned)w.z << 16);
            acc[5] += a * __uint_as_float((unsigned)w.z & 0xffff0000u);
            acc[6] += a * __uint_as_float((unsigned)w.w << 16);
            acc[7] += a * __uint_as_float((unsigned)w.w & 0xffff0000u);
        }
        int4 o;
        o.x = pk2(acc[0], acc[1]); o.y = pk2(acc[2], acc[3]);
        o.z = pk2(acc[4], acc[5]); o.w = pk2(acc[6], acc[7]);
        *(int4*)&Amat[j * LDK + c8 * 8] = o;
    }
    __syncthreads();

    // ---- P4: C[38x128] = Amat[38x256] * B[256x128] via MFMA 16x16x32 ----
    float* ob = out + (size_t)blockIdx.x * ROWS * 128;
    #pragma unroll
    for (int rt = 0; rt < 3; ++rt) {
        f32x4 acc0 = {0.f, 0.f, 0.f, 0.f};
        f32x4 acc1 = {0.f, 0.f, 0.f, 0.f};
        const unsigned short* ar = Amat + (rt * 16 + lrow) * LDK + kq;
        #pragma unroll
        for (int ks = 0; ks < 8; ++ks) {   // k = ks*32: 0..127 rel, 128..255 root
            short8 a = *(const short8*)(ar + ks * 32);
            int p = ks >> 2, k4 = ks & 3;
            acc0 = __builtin_amdgcn_mfma_f32_16x16x32_bf16(a, bf[p][0][k4], acc0, 0, 0, 0);
            acc1 = __builtin_amdgcn_mfma_f32_16x16x32_bf16(a, bf[p][1][k4], acc1, 0, 0, 0);
        }
        // C/D layout: col = lane&15, row = (lane>>4)*4 + reg
        int rbase = rt * 16 + (lane >> 4) * 4;
        #pragma unroll
        for (int r = 0; r < 4; ++r) {
            int row = rbase + r;
            if (row < ROWS) {
                ob[row * 128 + colA] = acc0[r] + bias0;
                ob[row * 128 + colB] = acc1[r] + bias1;
            }
        }
    }
}

extern "C" void kernel_launch(void* const* d_in, const int* in_sizes, int n_in,
                              void* d_out, int out_size, void* d_ws, size_t ws_size,
                              hipStream_t stream) {
    const float* x     = (const float*)d_in[0];
    const int*   ei    = (const int*)d_in[1];
    const float* ew    = (const float*)d_in[2];
    const float* Wrel  = (const float*)d_in[3];
    const float* brel  = (const float*)d_in[4];
    const float* Wroot = (const float*)d_in[5];
    float* out = (float*)d_out;

    const int E_total  = in_sizes[1] / 2;     // 615600
    const int n_graphs = E_total / EPG;       // 1800
    const int n_blocks = n_graphs / GPB;      // 900

    graphconv_mfma<<<n_blocks, 256, 0, stream>>>(
        x, ei, ew, Wrel, brel, Wroot, out, E_total);
}

// Round 5
// 99.862 us; speedup vs baseline: 6.1142x; 1.0695x over previous
//
#include <hip/hip_runtime.h>
#include <hip/hip_bf16.h>

#define GPB 4            // graphs per block (2 iterations x 2 graphs)
#define ITERS 2
#define RPI 38           // rows per iteration (2*19)
#define MP 48            // Amat rows (3 tiles of 16)
#define LDK 264          // Amat row stride in bf16 elems (528 B, 16B-aligned)
#define EPG 342          // edges per graph

typedef short short8 __attribute__((ext_vector_type(8)));
typedef float f32x4  __attribute__((ext_vector_type(4)));

static __device__ __forceinline__ unsigned int f2bf(float f) {
    unsigned int u = __float_as_uint(f);
    return (u + 0x7fffu + ((u >> 16) & 1u)) >> 16;   // RNE
}
static __device__ __forceinline__ int pk2(float lo, float hi) {
    return (int)(f2bf(lo) | (f2bf(hi) << 16));
}

__global__ __launch_bounds__(256) void graphconv_mfma(
    const float* __restrict__ x,
    const int*   __restrict__ ei,      // [2, E_total]
    const float* __restrict__ ew,      // [342]
    const float* __restrict__ Wrel,    // [128,128] row-major (co, ci)
    const float* __restrict__ brel,    // [128]
    const float* __restrict__ Wroot,   // [128,128]
    float* __restrict__ out,
    int E_total)
{
    // Amat[r][k] bf16: k in [0,128) = agg, [128,256) = x.  Reused per iteration.
    __shared__ __align__(16) unsigned short Amat[MP * LDK];   // 25344 B
    __shared__ float adj[GPB][19][20];                        //  6080 B (all 4 graphs)

    const int t    = threadIdx.x;
    const int lane = t & 63;
    const int wv   = t >> 6;
    const int g0   = blockIdx.x * GPB;

    // ---- issue iter-0 x loads FIRST: HBM latency overlaps all setup below ----
    const float4* xg0 = (const float4*)(x + (size_t)g0 * 19 * 128);
    float4 xc[5];
    #pragma unroll
    for (int q = 0; q < 5; ++q) {
        int idx = t + q * 256;
        if (idx < RPI * 32) xc[q] = xg0[idx];
    }

    // ---- zero adj ----
    for (int i = t; i < GPB * 19 * 20; i += 256) ((float*)adj)[i] = 0.f;
    __syncthreads();

    // ---- scatter ALL 4 graphs' edges into adjacency (once per block) ----
    for (int e = t; e < GPB * EPG; e += 256) {
        int g  = e / EPG;                  // 0..3
        int te = e - g * EPG;
        int ge = g0 * EPG + e;
        int nb = (g0 + g) * 19;
        int sl = ei[ge] - nb;              // row 0: src
        int dl = ei[E_total + ge] - nb;    // row 1: dst
        adj[g][dl][sl] = ew[te];           // rep[ge] = ew[te]
    }

    // ---- W fragments in registers (ONCE per block, amortized over 4 graphs).
    // B-frag layout (verified R3/R4 pass): lane holds B[k=kq+j][n] = W[n][kq+j].
    const int lrow = lane & 15;
    const int kq   = (lane >> 4) * 8;
    const int colA = wv * 16 + lrow;
    const int colB = (wv + 4) * 16 + lrow;

    short8 bf[2][2][4];   // [rel/root][col-tile][k-step]
    #pragma unroll
    for (int pass = 0; pass < 2; ++pass) {
        const float* W = pass ? Wroot : Wrel;
        #pragma unroll
        for (int ct = 0; ct < 2; ++ct) {
            const float* wr = W + (size_t)(ct ? colB : colA) * 128 + kq;
            #pragma unroll
            for (int ks = 0; ks < 4; ++ks) {
                const float4* p = (const float4*)(wr + ks * 32);
                float4 a = p[0], b = p[1];
                union { short8 s; int i[4]; } u;
                u.i[0] = pk2(a.x, a.y); u.i[1] = pk2(a.z, a.w);
                u.i[2] = pk2(b.x, b.y); u.i[3] = pk2(b.z, b.w);
                bf[pass][ct][ks] = u.s;
            }
        }
    }
    const float bias0 = brel[colA];
    const float bias1 = brel[colB];

    float4 xn[5];
    __syncthreads();   // adj complete

    #pragma unroll
    for (int it = 0; it < ITERS; ++it) {
        // ---- commit current x regs -> Amat[:,128:256) as bf16 ----
        #pragma unroll
        for (int q = 0; q < 5; ++q) {
            int idx = t + q * 256;
            if (idx < RPI * 32) {
                int row = idx >> 5, c4 = idx & 31;
                float4 v = xc[q];
                int2 w; w.x = pk2(v.x, v.y); w.y = pk2(v.z, v.w);
                *(int2*)&Amat[row * LDK + 128 + c4 * 4] = w;
            }
        }
        __syncthreads();

        // ---- prefetch next iteration's x (latency hidden under P3+P4) ----
        if (it + 1 < ITERS) {
            const float4* xg = (const float4*)(x + (size_t)(g0 + (it + 1) * 2) * 19 * 128);
            #pragma unroll
            for (int q = 0; q < 5; ++q) {
                int idx = t + q * 256;
                if (idx < RPI * 32) xn[q] = xg[idx];
            }
        }

        // ---- P3: agg[j][c] = sum_i adj[j][i]*x[i][c] -> Amat[:,0:128) ----
        for (int idx = t; idx < RPI * 16; idx += 256) {
            int j = idx >> 4, c8 = idx & 15;
            int hi = (j >= 19);
            int gl = 2 * it + hi;
            int jl = j - 19 * hi;
            int bg = 19 * hi;
            float acc[8];
            #pragma unroll
            for (int q = 0; q < 8; ++q) acc[q] = 0.f;
            #pragma unroll 4
            for (int i = 0; i < 19; ++i) {
                float a = adj[gl][jl][i];
                int4 w = *(const int4*)&Amat[(bg + i) * LDK + 128 + c8 * 8];
                acc[0] += a * __uint_as_float((unsigned)w.x << 16);
                acc[1] += a * __uint_as_float((unsigned)w.x & 0xffff0000u);
                acc[2] += a * __uint_as_float((unsigned)w.y << 16);
                acc[3] += a * __uint_as_float((unsigned)w.y & 0xffff0000u);
                acc[4] += a * __uint_as_float((unsigned)w.z << 16);
                acc[5] += a * __uint_as_float((unsigned)w.z & 0xffff0000u);
                acc[6] += a * __uint_as_float((unsigned)w.w << 16);
                acc[7] += a * __uint_as_float((unsigned)w.w & 0xffff0000u);
            }
            int4 o;
            o.x = pk2(acc[0], acc[1]); o.y = pk2(acc[2], acc[3]);
            o.z = pk2(acc[4], acc[5]); o.w = pk2(acc[6], acc[7]);
            *(int4*)&Amat[j * LDK + c8 * 8] = o;
        }
        __syncthreads();

        // ---- P4: C[38x128] = Amat[38x256] * B[256x128] via MFMA ----
        float* ob = out + (size_t)(g0 + it * 2) * 19 * 128;
        #pragma unroll
        for (int rt = 0; rt < 3; ++rt) {
            f32x4 acc0 = {0.f, 0.f, 0.f, 0.f};
            f32x4 acc1 = {0.f, 0.f, 0.f, 0.f};
            const unsigned short* ar = Amat + (rt * 16 + lrow) * LDK + kq;
            #pragma unroll
            for (int ks = 0; ks < 8; ++ks) {
                short8 a = *(const short8*)(ar + ks * 32);
                int p = ks >> 2, k4 = ks & 3;
                acc0 = __builtin_amdgcn_mfma_f32_16x16x32_bf16(a, bf[p][0][k4], acc0, 0, 0, 0);
                acc1 = __builtin_amdgcn_mfma_f32_16x16x32_bf16(a, bf[p][1][k4], acc1, 0, 0, 0);
            }
            int rbase = rt * 16 + (lane >> 4) * 4;
            #pragma unroll
            for (int r = 0; r < 4; ++r) {
                int row = rbase + r;
                if (row < RPI) {
                    ob[row * 128 + colA] = acc0[r] + bias0;
                    ob[row * 128 + colB] = acc1[r] + bias1;
                }
            }
        }
        __syncthreads();   // Amat readers done before next commit

        #pragma unroll
        for (int q = 0; q < 5; ++q) xc[q] = xn[q];
    }
}

extern "C" void kernel_launch(void* const* d_in, const int* in_sizes, int n_in,
                              void* d_out, int out_size, void* d_ws, size_t ws_size,
                              hipStream_t stream) {
    const float* x     = (const float*)d_in[0];
    const int*   ei    = (const int*)d_in[1];
    const float* ew    = (const float*)d_in[2];
    const float* Wrel  = (const float*)d_in[3];
    const float* brel  = (const float*)d_in[4];
    const float* Wroot = (const float*)d_in[5];
    float* out = (float*)d_out;

    const int E_total  = in_sizes[1] / 2;     // 615600
    const int n_graphs = E_total / EPG;       // 1800
    const int n_blocks = n_graphs / GPB;      // 450

    graphconv_mfma<<<n_blocks, 256, 0, stream>>>(
        x, ei, ew, Wrel, brel, Wroot, out, E_total);
}